// Round 2
// baseline (10813.432 us; speedup 1.0000x reference)
//
#include <hip/hip_runtime.h>
#include <hip/hip_bf16.h>

typedef __hip_bfloat16 bf16;

constexpr int N_LAYER = 6;
constexpr int N_HEAD  = 12;
constexpr int HEAD_D  = 64;
constexpr int N_EMB   = 768;
constexpr int N_VOCAB = 32000;
constexpr int N_B     = 2;
constexpr int N_T     = 1024;
constexpr int N_M     = N_B * N_T;      // 2048
constexpr float LN_EPS = 1e-5f;
constexpr float ATT_SCALE = 0.03608439182435161f; // 768^-0.5 (reference scales by C^-0.5)

__device__ __forceinline__ float b2f(bf16 v) { return __bfloat162float(v); }
__device__ __forceinline__ float us2f(unsigned short u) {
    union { unsigned int i; float f; } c; c.i = ((unsigned int)u) << 16; return c.f;
}

// Dual-dtype scalar load: isf=1 -> buffer is fp32, else bf16.
// if/else (not ?:) so the untaken load is never speculated (it would be OOB).
__device__ __forceinline__ float ldw(const void* p, int isf, size_t i) {
    if (isf) return ((const float*)p)[i];
    return b2f(((const bf16*)p)[i]);
}

// ---------------- dtype detection: inspect tok_emb raw words ----------------
// bf16 data: both halves of every word decode to |v| < 0.5 (weights ~N(0,0.02)).
// fp32 data: low halves are mantissa noise -> ~50% decode to |v|>=0.5 or NaN.
__global__ __launch_bounds__(256) void detect_kernel(const unsigned int* __restrict__ w,
                                                     int* __restrict__ flag)
{
    __shared__ int red[256];
    int cnt = 0;
    for (int i = threadIdx.x; i < 4096; i += 256) {
        unsigned int u = w[i];
        float flo = us2f((unsigned short)(u & 0xffffu));
        float fhi = us2f((unsigned short)(u >> 16));
        if (!(fabsf(flo) < 0.5f)) cnt++;   // NaN also counts (comparison false)
        if (!(fabsf(fhi) < 0.5f)) cnt++;
    }
    red[threadIdx.x] = cnt;
    __syncthreads();
    for (int off = 128; off > 0; off >>= 1) {
        if (threadIdx.x < off) red[threadIdx.x] += red[threadIdx.x + off];
        __syncthreads();
    }
    if (threadIdx.x == 0) flag[0] = (red[0] > 64) ? 1 : 0;  // 1 = inputs are fp32
}

// ---------------- embedding: h = tok_emb[x] + pos_emb ----------------
__global__ __launch_bounds__(256) void embed_kernel(const int* __restrict__ x,
        const void* __restrict__ tok, const void* __restrict__ pos,
        const int* __restrict__ flag, float* __restrict__ h)
{
    const int isf = *flag;
    int idx = blockIdx.x * 256 + threadIdx.x;
    if (idx >= N_M * N_EMB) return;
    int m = idx / N_EMB, c = idx - m * N_EMB;
    int t = m & (N_T - 1);
    int tokid = x[m];
    h[idx] = ldw(tok, isf, (size_t)tokid * N_EMB + c) + ldw(pos, isf, (size_t)t * N_EMB + c);
}

// ---------------- layernorm: one block per row ----------------
__global__ __launch_bounds__(256) void ln_kernel(const float* __restrict__ in,
        const void* __restrict__ g, const void* __restrict__ b, size_t gofs,
        const int* __restrict__ flag, float* __restrict__ out)
{
    __shared__ float red[256];
    const int isf = *flag;
    const int tid = threadIdx.x;
    const float* row = in + (size_t)blockIdx.x * N_EMB;
    float v0 = row[tid], v1 = row[tid + 256], v2 = row[tid + 512];
    red[tid] = v0 + v1 + v2;
    __syncthreads();
    for (int off = 128; off > 0; off >>= 1) {
        if (tid < off) red[tid] += red[tid + off];
        __syncthreads();
    }
    float mean = red[0] * (1.0f / N_EMB);
    __syncthreads();
    float d0 = v0 - mean, d1 = v1 - mean, d2 = v2 - mean;
    red[tid] = d0 * d0 + d1 * d1 + d2 * d2;
    __syncthreads();
    for (int off = 128; off > 0; off >>= 1) {
        if (tid < off) red[tid] += red[tid + off];
        __syncthreads();
    }
    float inv = rsqrtf(red[0] * (1.0f / N_EMB) + LN_EPS);
    float* orow = out + (size_t)blockIdx.x * N_EMB;
    orow[tid]       = d0 * inv * ldw(g, isf, gofs + tid)       + ldw(b, isf, gofs + tid);
    orow[tid + 256] = d1 * inv * ldw(g, isf, gofs + tid + 256) + ldw(b, isf, gofs + tid + 256);
    orow[tid + 512] = d2 * inv * ldw(g, isf, gofs + tid + 512) + ldw(b, isf, gofs + tid + 512);
}

// ---------------- generic GEMM: C = A(f32 ws, MxK) * B(weights, KxN) ----------------
// 128x128 tile, BK=16, 256 threads, 8x8 per thread, fp32 accumulate.
// outB != nullptr -> final output (dtype per flag); else outF (fp32 ws).
__global__ __launch_bounds__(256) void gemm_kernel(
    const float* __restrict__ A, const void* __restrict__ Bw, size_t Bofs,
    const void* __restrict__ bias, size_t biasOfs,
    const float* __restrict__ resid,
    float* __restrict__ outF, void* __restrict__ outB,
    const int* __restrict__ flag, int Ndim, int K, int relu)
{
    __shared__ float As[16][132];   // [k][m]
    __shared__ float Bs[16][132];   // [k][n]
    const int isf = *flag;
    const int tid = threadIdx.x;
    const int tx = tid & 15, ty = tid >> 4;
    const int m0 = blockIdx.x * 128, n0 = blockIdx.y * 128;

    const int amm = tid >> 1;          // 0..127
    const int akc = (tid & 1) * 8;     // 0 or 8
    const int bkk = tid >> 4;          // 0..15
    const int bnn = (tid & 15) * 8;    // 0..120

    float acc[8][8];
    #pragma unroll
    for (int i = 0; i < 8; i++)
        #pragma unroll
        for (int j = 0; j < 8; j++) acc[i][j] = 0.0f;

    for (int kt = 0; kt < K; kt += 16) {
        const float* ap = A + (size_t)(m0 + amm) * K + kt + akc;
        float4 a0 = *(const float4*)ap;
        float4 a1 = *(const float4*)(ap + 4);
        float bt[8];
        const size_t bbase = Bofs + (size_t)(kt + bkk) * Ndim + n0 + bnn;
        #pragma unroll
        for (int j = 0; j < 8; j++) bt[j] = ldw(Bw, isf, bbase + j);
        __syncthreads();   // previous iteration's readers are done
        As[akc + 0][amm] = a0.x; As[akc + 1][amm] = a0.y;
        As[akc + 2][amm] = a0.z; As[akc + 3][amm] = a0.w;
        As[akc + 4][amm] = a1.x; As[akc + 5][amm] = a1.y;
        As[akc + 6][amm] = a1.z; As[akc + 7][amm] = a1.w;
        #pragma unroll
        for (int j = 0; j < 8; j++) Bs[bkk][bnn + j] = bt[j];
        __syncthreads();
        #pragma unroll
        for (int kk = 0; kk < 16; kk++) {
            float4 x0 = *(const float4*)&As[kk][ty * 8];
            float4 x1 = *(const float4*)&As[kk][ty * 8 + 4];
            float4 y0 = *(const float4*)&Bs[kk][tx * 8];
            float4 y1 = *(const float4*)&Bs[kk][tx * 8 + 4];
            float xa[8] = {x0.x, x0.y, x0.z, x0.w, x1.x, x1.y, x1.z, x1.w};
            float yb[8] = {y0.x, y0.y, y0.z, y0.w, y1.x, y1.y, y1.z, y1.w};
            #pragma unroll
            for (int i = 0; i < 8; i++)
                #pragma unroll
                for (int j = 0; j < 8; j++)
                    acc[i][j] = fmaf(xa[i], yb[j], acc[i][j]);
        }
    }
    #pragma unroll
    for (int i = 0; i < 8; i++) {
        const int row = m0 + ty * 8 + i;
        const size_t rbase = (size_t)row * Ndim;
        #pragma unroll
        for (int j = 0; j < 8; j++) {
            const int col = n0 + tx * 8 + j;
            float vv = acc[i][j];
            if (bias)  vv += ldw(bias, isf, biasOfs + col);
            if (resid) vv += resid[rbase + col];
            if (relu)  vv = fmaxf(vv, 0.0f);
            if (outB) {
                if (isf) ((float*)outB)[rbase + col] = vv;
                else     ((bf16*)outB)[rbase + col] = __float2bfloat16(vv);
            } else {
                outF[rbase + col] = vv;
            }
        }
    }
}

// ---------------- QKV: per-head 2048x64x768 GEMMs, out layout (B,H,T,D) ----------------
__global__ __launch_bounds__(256) void qkv_kernel(
    const float* __restrict__ A, const void* __restrict__ Wq,
    const void* __restrict__ Wk, const void* __restrict__ Wv, size_t wbase,
    const int* __restrict__ flag,
    float* __restrict__ qo, float* __restrict__ ko, float* __restrict__ vo)
{
    __shared__ float As[16][68];
    __shared__ float Bs[16][68];
    const int isf = *flag;
    const int tid = threadIdx.x;
    const int tx = tid & 15, ty = tid >> 4;
    const int m0 = blockIdx.x * 64;
    const int which = blockIdx.y / N_HEAD;
    const int h = blockIdx.y % N_HEAD;
    const void* W = (which == 0 ? Wq : (which == 1 ? Wk : Wv));
    const size_t base = wbase + (size_t)h * N_EMB * HEAD_D;
    float* O = (which == 0 ? qo : (which == 1 ? ko : vo));

    const int amm = tid >> 2;         // 0..63
    const int akc = (tid & 3) * 4;    // 0,4,8,12
    const int bkk = tid >> 4;         // 0..15
    const int bnn = (tid & 15) * 4;   // 0..60

    float acc[4][4] = {};
    for (int kt = 0; kt < N_EMB; kt += 16) {
        float4 a4 = *(const float4*)(A + (size_t)(m0 + amm) * N_EMB + kt + akc);
        float bt[4];
        const size_t wofs = base + (size_t)(kt + bkk) * HEAD_D + bnn;
        #pragma unroll
        for (int j = 0; j < 4; j++) bt[j] = ldw(W, isf, wofs + j);
        __syncthreads();
        As[akc + 0][amm] = a4.x; As[akc + 1][amm] = a4.y;
        As[akc + 2][amm] = a4.z; As[akc + 3][amm] = a4.w;
        #pragma unroll
        for (int j = 0; j < 4; j++) Bs[bkk][bnn + j] = bt[j];
        __syncthreads();
        #pragma unroll
        for (int kk = 0; kk < 16; kk++) {
            float4 x = *(const float4*)&As[kk][ty * 4];
            float4 y = *(const float4*)&Bs[kk][tx * 4];
            float xa[4] = {x.x, x.y, x.z, x.w};
            float yb[4] = {y.x, y.y, y.z, y.w};
            #pragma unroll
            for (int i = 0; i < 4; i++)
                #pragma unroll
                for (int j = 0; j < 4; j++)
                    acc[i][j] = fmaf(xa[i], yb[j], acc[i][j]);
        }
    }
    #pragma unroll
    for (int i = 0; i < 4; i++) {
        int m = m0 + ty * 4 + i;
        int bb = m >> 10, t = m & (N_T - 1);
        float* op = O + (((size_t)(bb * N_HEAD + h)) * N_T + t) * HEAD_D + tx * 4;
        op[0] = acc[i][0]; op[1] = acc[i][1]; op[2] = acc[i][2]; op[3] = acc[i][3];
    }
}

// ---------------- flash attention: one block per (q-tile, head, batch) ----------------
__global__ __launch_bounds__(256) void attn_kernel(
    const float* __restrict__ q, const float* __restrict__ k, const float* __restrict__ v,
    float* __restrict__ o)
{
    __shared__ float Qs[64][68];
    __shared__ float KS[64][68];   // K tile, then reused for P
    __shared__ float Vs[64][68];
    __shared__ float mrow[64], lrow[64], arow[64];
    const int tq = blockIdx.x;
    const int h = blockIdx.y, b = blockIdx.z;
    const int tid = threadIdx.x;
    const int tx = tid & 15, ty = tid >> 4;
    const size_t base = ((size_t)(b * N_HEAD + h)) * N_T * HEAD_D;
    const float* qb = q + base;
    const float* kb = k + base;
    const float* vb = v + base;

    const int rr = tid >> 2;          // 0..63
    const int cc = (tid & 3) * 16;    // 0,16,32,48
    {
        const float* src = qb + (size_t)(tq * 64 + rr) * HEAD_D + cc;
        #pragma unroll
        for (int j = 0; j < 16; j += 4)
            *(float4*)&Qs[rr][cc + j] = *(const float4*)(src + j);
    }
    if (tid < 64) { mrow[tid] = -1e30f; lrow[tid] = 0.0f; }
    float oa[4][4] = {};

    for (int kt = 0; kt <= tq; kt++) {
        __syncthreads();  // prior readers of KS/Vs done
        {
            const float* ks = kb + (size_t)(kt * 64 + rr) * HEAD_D + cc;
            const float* vs = vb + (size_t)(kt * 64 + rr) * HEAD_D + cc;
            #pragma unroll
            for (int j = 0; j < 16; j += 4) {
                *(float4*)&KS[rr][cc + j] = *(const float4*)(ks + j);
                *(float4*)&Vs[rr][cc + j] = *(const float4*)(vs + j);
            }
        }
        __syncthreads();
        // S = Q K^T (4x4 per thread)
        float s[4][4] = {};
        #pragma unroll
        for (int kk = 0; kk < 64; kk += 4) {
            float4 qv[4], kv[4];
            #pragma unroll
            for (int i = 0; i < 4; i++) qv[i] = *(const float4*)&Qs[ty * 4 + i][kk];
            #pragma unroll
            for (int j = 0; j < 4; j++) kv[j] = *(const float4*)&KS[tx * 4 + j][kk];
            #pragma unroll
            for (int i = 0; i < 4; i++)
                #pragma unroll
                for (int j = 0; j < 4; j++)
                    s[i][j] += qv[i].x * kv[j].x + qv[i].y * kv[j].y +
                               qv[i].z * kv[j].z + qv[i].w * kv[j].w;
        }
        const int qr0 = tq * 64 + ty * 4, kc0 = kt * 64 + tx * 4;
        #pragma unroll
        for (int i = 0; i < 4; i++)
            #pragma unroll
            for (int j = 0; j < 4; j++)
                s[i][j] = (kc0 + j <= qr0 + i) ? s[i][j] * ATT_SCALE : -1e30f;
        __syncthreads();  // done reading KS as K
        #pragma unroll
        for (int i = 0; i < 4; i++)
            #pragma unroll
            for (int j = 0; j < 4; j++)
                KS[ty * 4 + i][tx * 4 + j] = s[i][j];
        __syncthreads();
        // online-softmax row stats: 4 threads per row (same wave -> shfl over 16-col parts)
        {
            const int r = tid >> 2, part = tid & 3;
            const int c0 = part * 16;
            float mo = mrow[r];
            float mx = -1e30f;
            #pragma unroll
            for (int c = 0; c < 16; c++) mx = fmaxf(mx, KS[r][c0 + c]);
            mx = fmaxf(mx, __shfl_xor(mx, 1));
            mx = fmaxf(mx, __shfl_xor(mx, 2));
            mx = fmaxf(mx, mo);
            float sum = 0.0f;
            #pragma unroll
            for (int c = 0; c < 16; c++) {
                float p = __expf(KS[r][c0 + c] - mx);
                KS[r][c0 + c] = p;
                sum += p;
            }
            sum += __shfl_xor(sum, 1);
            sum += __shfl_xor(sum, 2);
            if (part == 0) {
                float al = __expf(mo - mx);
                mrow[r] = mx;
                lrow[r] = lrow[r] * al + sum;
                arow[r] = al;
            }
        }
        __syncthreads();
        // O = O*alpha + P V
        #pragma unroll
        for (int i = 0; i < 4; i++) {
            float al = arow[ty * 4 + i];
            #pragma unroll
            for (int j = 0; j < 4; j++) oa[i][j] *= al;
        }
        #pragma unroll
        for (int ss = 0; ss < 64; ss += 4) {
            float4 p4[4], v4[4];
            #pragma unroll
            for (int i = 0; i < 4; i++) p4[i] = *(const float4*)&KS[ty * 4 + i][ss];
            #pragma unroll
            for (int s2 = 0; s2 < 4; s2++) v4[s2] = *(const float4*)&Vs[ss + s2][tx * 4];
            #pragma unroll
            for (int i = 0; i < 4; i++) {
                float4 P = p4[i];
                oa[i][0] += P.x * v4[0].x + P.y * v4[1].x + P.z * v4[2].x + P.w * v4[3].x;
                oa[i][1] += P.x * v4[0].y + P.y * v4[1].y + P.z * v4[2].y + P.w * v4[3].y;
                oa[i][2] += P.x * v4[0].z + P.y * v4[1].z + P.z * v4[2].z + P.w * v4[3].z;
                oa[i][3] += P.x * v4[0].w + P.y * v4[1].w + P.z * v4[2].w + P.w * v4[3].w;
            }
        }
    }
    // epilogue: divide by row sum, write (B,T,H*D)
    #pragma unroll
    for (int i = 0; i < 4; i++) {
        int r = ty * 4 + i;
        int t = tq * 64 + r;
        float invl = 1.0f / lrow[r];
        float* op = o + (((size_t)(b * N_T + t)) * N_HEAD + h) * HEAD_D + tx * 4;
        op[0] = oa[i][0] * invl; op[1] = oa[i][1] * invl;
        op[2] = oa[i][2] * invl; op[3] = oa[i][3] * invl;
    }
}

extern "C" void kernel_launch(void* const* d_in, const int* in_sizes, int n_in,
                              void* d_out, int out_size, void* d_ws, size_t ws_size,
                              hipStream_t stream)
{
    const int*  x    = (const int*) d_in[0];
    const void* tok  = d_in[1];
    const void* pos  = d_in[2];
    const void* Wq   = d_in[3];
    const void* Wk   = d_in[4];
    const void* Wv   = d_in[5];
    const void* Wo   = d_in[6];
    const void* bo   = d_in[7];
    const void* ln1g = d_in[8];
    const void* ln1b = d_in[9];
    const void* ln2g = d_in[10];
    const void* ln2b = d_in[11];
    const void* W1   = d_in[12];
    const void* b1   = d_in[13];
    const void* W2   = d_in[14];
    const void* b2   = d_in[15];
    const void* lnfg = d_in[16];
    const void* lnfb = d_in[17];
    const void* Wh   = d_in[18];
    const void* bh   = d_in[19];

    float* ws = (float*)d_ws;
    int* flag = (int*)ws;                // 64-float slot for the dtype flag
    const size_t MC = (size_t)N_M * N_EMB;
    float* h   = ws + 64;                // (M, C)
    float* a   = h + MC;                 // ln out / attn out (M, C)
    float* big = a + MC;                 // q,k,v (3*MC) overlapped later by ffn hidden (4*MC)
    float* qb  = big;
    float* kb  = big + MC;
    float* vb  = big + 2 * MC;
    float* ffh = big;                    // (M, 4C) — q/k/v dead by FFN time

    detect_kernel<<<1, 256, 0, stream>>>((const unsigned int*)tok, flag);

    embed_kernel<<<(int)((MC + 255) / 256), 256, 0, stream>>>(x, tok, pos, flag, h);

    for (int l = 0; l < N_LAYER; l++) {
        ln_kernel<<<N_M, 256, 0, stream>>>(h, ln1g, ln1b, (size_t)l * N_EMB, flag, a);

        dim3 gq(N_M / 64, 3 * N_HEAD);
        const size_t wbase = (size_t)l * N_HEAD * N_EMB * HEAD_D;
        qkv_kernel<<<gq, 256, 0, stream>>>(a, Wq, Wk, Wv, wbase, flag, qb, kb, vb);

        dim3 ga(N_T / 64, N_HEAD, N_B);
        attn_kernel<<<ga, 256, 0, stream>>>(qb, kb, vb, a);   // a := attn out (B,T,H*D)

        dim3 gp(N_M / 128, N_EMB / 128);
        gemm_kernel<<<gp, 256, 0, stream>>>(a, Wo, (size_t)l * N_EMB * N_EMB,
                                            bo, (size_t)l * N_EMB, h, h, nullptr,
                                            flag, N_EMB, N_EMB, 0);

        ln_kernel<<<N_M, 256, 0, stream>>>(h, ln2g, ln2b, (size_t)l * N_EMB, flag, a);

        dim3 g1(N_M / 128, (4 * N_EMB) / 128);
        gemm_kernel<<<g1, 256, 0, stream>>>(a, W1, (size_t)l * N_EMB * 4 * N_EMB,
                                            b1, (size_t)l * 4 * N_EMB, nullptr, ffh, nullptr,
                                            flag, 4 * N_EMB, N_EMB, 1);

        dim3 g2(N_M / 128, N_EMB / 128);
        gemm_kernel<<<g2, 256, 0, stream>>>(ffh, W2, (size_t)l * 4 * N_EMB * N_EMB,
                                            b2, (size_t)l * N_EMB, h, h, nullptr,
                                            flag, N_EMB, 4 * N_EMB, 0);
    }

    ln_kernel<<<N_M, 256, 0, stream>>>(h, lnfg, lnfb, 0, flag, a);

    dim3 gh(N_M / 128, N_VOCAB / 128);
    gemm_kernel<<<gh, 256, 0, stream>>>(a, Wh, 0, bh, 0, nullptr, nullptr, d_out,
                                        flag, N_VOCAB, N_EMB, 0);
}